// Round 6
// baseline (105.321 us; speedup 1.0000x reference)
//
#include <hip/hip_runtime.h>
#include <math.h>

#define TT 8
#define CC 256
#define C4 64
#define KK 3
#define HW 3136    // 56*56
#define HW4 784    // HW/4
#define NCLIP 8
#define BN_EPS 1e-5f

typedef float f32x4 __attribute__((ext_vector_type(4)));

// ---------------- Kernel 1: spatial mean pool ----------------
// pooled[n][c][t] = mean over 56x56 of x[(n*8+t), c, :, :]
// Regular (allocating) loads: this pass populates L3 with x for tam_apply.
__global__ __launch_bounds__(256) void tam_pool(const float* __restrict__ x,
                                                float* __restrict__ pooled) {
    int b = blockIdx.x;            // b = n*2048 + c*8 + t
    int n = b >> 11;
    int c = (b >> 3) & 255;
    int t = b & 7;
    const float4* xr = (const float4*)(x + ((size_t)((n * TT + t) * CC + c)) * HW);
    float s = 0.f;
    for (int i = threadIdx.x; i < HW4; i += 256) {
        float4 v = xr[i];
        s += v.x + v.y + v.z + v.w;
    }
    #pragma unroll
    for (int off = 32; off > 0; off >>= 1) s += __shfl_down(s, off, 64);
    __shared__ float ls[4];
    int lane = threadIdx.x & 63, wv = threadIdx.x >> 6;
    if (lane == 0) ls[wv] = s;
    __syncthreads();
    if (threadIdx.x == 0) {
        float tot = ls[0] + ls[1] + ls[2] + ls[3];
        pooled[(n * CC + c) * TT + t] = tot * (1.f / (float)HW);
    }
}

// ---------------- Kernel 2a: L-branch conv1 + BN + ReLU ----------------
__global__ __launch_bounds__(256) void tam_branch_a(
    const float* __restrict__ pooled, const float* __restrict__ l_w1,
    const float* __restrict__ l_bn_gamma, const float* __restrict__ l_bn_beta,
    const float* __restrict__ l_bn_mean, const float* __restrict__ l_bn_var,
    float* __restrict__ szws)          // [8][64][8]
{
    int n = blockIdx.x >> 6;
    int j = blockIdx.x & 63;
    int tid = threadIdx.x;
    __shared__ float sw[CC * KK];      // l_w1 row j: [i*3+k]
    __shared__ float sp[CC * 9];       // pooled clip n, rows padded to 9
    __shared__ float red[4][8];

    const float4* wsrc = (const float4*)(l_w1 + (size_t)j * (CC * KK));
    if (tid < 192) {
        float4 v = wsrc[tid];
        float* d = sw + tid * 4;
        d[0] = v.x; d[1] = v.y; d[2] = v.z; d[3] = v.w;
    }
    const float4* psrc = (const float4*)(pooled + (size_t)n * CC * TT);
    for (int q = tid; q < 512; q += 256) {
        float4 v = psrc[q];
        int c = q >> 1, e = (q & 1) * 4;
        float* d = sp + c * 9 + e;
        d[0] = v.x; d[1] = v.y; d[2] = v.z; d[3] = v.w;
    }
    __syncthreads();

    int t = tid & 7, ic = tid >> 3;    // ic in 0..31, 8 i-values each
    float acc = 0.f;
    #pragma unroll
    for (int m = 0; m < 8; ++m) {
        int i = ic * 8 + m;
        float p0 = (t > 0) ? sp[i * 9 + t - 1] : 0.f;
        float p1 =           sp[i * 9 + t];
        float p2 = (t < 7) ? sp[i * 9 + t + 1] : 0.f;
        acc += sw[i * 3 + 0] * p0 + sw[i * 3 + 1] * p1 + sw[i * 3 + 2] * p2;
    }
    acc += __shfl_down(acc, 32, 64);
    acc += __shfl_down(acc, 16, 64);
    acc += __shfl_down(acc, 8, 64);
    int lane = tid & 63, wv = tid >> 6;
    if (lane < 8) red[wv][lane] = acc;
    __syncthreads();
    if (tid < 8) {
        float z = red[0][tid] + red[1][tid] + red[2][tid] + red[3][tid];
        float scale = l_bn_gamma[j] * rsqrtf(l_bn_var[j] + BN_EPS);
        z = (z - l_bn_mean[j]) * scale + l_bn_beta[j];
        szws[((size_t)n * C4 + j) * TT + tid] = fmaxf(z, 0.f);
    }
}

// ---------------- Kernel 2b: act (1x1 conv + sigmoid) + G branch -> coef ----------------
__global__ __launch_bounds__(256) void tam_branch_b(
    const float* __restrict__ pooled, const float* __restrict__ szws,
    const float* __restrict__ l_w2,
    const float* __restrict__ g_w1, const float* __restrict__ g_bn_gamma,
    const float* __restrict__ g_bn_beta, const float* __restrict__ g_bn_mean,
    const float* __restrict__ g_bn_var, const float* __restrict__ g_w2,
    float* __restrict__ coef)
{
    int n = blockIdx.x >> 3;
    int cg = blockIdx.x & 7;           // channels cg*32 .. cg*32+31
    int tid = threadIdx.x;
    __shared__ float ssz[C4 * TT];     // sz[j][t], j-major
    __shared__ float sw2[32 * 65];     // l_w2 rows, padded to 65
    __shared__ float spr[32 * 9];      // pooled rows, padded to 9
    __shared__ float sg1[16 * 8];      // g_w1 [o][i]
    __shared__ float sbn[32];          // scale[o], shift[o]
    __shared__ float sg2[48];          // g_w2 [k][o]

    {
        const float4* s = (const float4*)(szws + (size_t)n * C4 * TT);
        if (tid < 128) ((float4*)ssz)[tid] = s[tid];
        const float4* p = (const float4*)(pooled + ((size_t)n * CC + cg * 32) * TT);
        if (tid >= 128 && tid < 192) {
            int q = tid - 128;
            float4 v = p[q];
            int cc = q >> 1, e = (q & 1) * 4;
            float* d = spr + cc * 9 + e;
            d[0] = v.x; d[1] = v.y; d[2] = v.z; d[3] = v.w;
        }
        if (tid >= 192 && tid < 224) ((float4*)sg1)[tid - 192] = ((const float4*)g_w1)[tid - 192];
        if (tid >= 224 && tid < 240) {
            int o = tid - 224;
            float sc = g_bn_gamma[o] * rsqrtf(g_bn_var[o] + BN_EPS);
            sbn[o] = sc;
            sbn[16 + o] = g_bn_beta[o] - g_bn_mean[o] * sc;
        }
    }
    {
        const float4* w = (const float4*)(l_w2 + (size_t)(cg * 32) * C4);
        for (int q = tid; q < 512; q += 256) {
            float4 v = w[q];
            int cc = q >> 4, e = (q & 15) * 4;
            float* d = sw2 + cc * 65 + e;
            d[0] = v.x; d[1] = v.y; d[2] = v.z; d[3] = v.w;
        }
        if (tid < 48) sg2[tid] = g_w2[tid];
    }
    __syncthreads();

    int t = tid & 7, cc = tid >> 3;    // cc in 0..31
    float a = 0.f;
    #pragma unroll 16
    for (int j = 0; j < C4; ++j) a += sw2[cc * 65 + j] * ssz[j * TT + t];
    float act = 1.f / (1.f + __expf(-a));

    float y[16];
    #pragma unroll
    for (int o = 0; o < 16; ++o) {
        float s = 0.f;
        #pragma unroll
        for (int i = 0; i < TT; ++i) s += sg1[o * 8 + i] * spr[cc * 9 + i];
        y[o] = fmaxf(s * sbn[o] + sbn[16 + o], 0.f);
    }
    float k3[KK];
    float mx = -1e30f;
    #pragma unroll
    for (int kk = 0; kk < KK; ++kk) {
        float s = 0.f;
        #pragma unroll
        for (int o = 0; o < 16; ++o) s += sg2[kk * 16 + o] * y[o];
        k3[kk] = s;
        mx = fmaxf(mx, s);
    }
    float se = 0.f;
    #pragma unroll
    for (int kk = 0; kk < KK; ++kk) { k3[kk] = __expf(k3[kk] - mx); se += k3[kk]; }
    float inv = 1.f / se;

    int lane = tid & 63;
    float am = __shfl(act, lane - 1, 64);   // valid when t>0
    float ap = __shfl(act, lane + 1, 64);   // valid when t<7

    float* cf = coef + ((size_t)(n * CC + cg * 32 + cc)) * 24 + t * 3;
    cf[0] = (t > 0) ? k3[0] * inv * am : 0.f;
    cf[1] =           k3[1] * inv * act;
    cf[2] = (t < 7) ? k3[2] * inv * ap : 0.f;
}

// ---------------- Kernel 3: gated temporal depthwise conv ----------------
// NT LOADS on x: demote-after-use. Consumed x lines become the eviction
// victims for this kernel's own write-allocations, so the unread tail of
// x (populated by tam_pool) stays L3-resident and reads hit L3.
// NT stores: out is never re-read.
__global__ __launch_bounds__(256) void tam_apply(const float* __restrict__ x,
                                                 const float* __restrict__ coef,
                                                 float* __restrict__ out)
{
    int bid = gridDim.x - 1 - blockIdx.x;      // reversed block order
    int id = bid * 256 + threadIdx.x;          // 0 .. 2048*784-1 (exact)
    int nc = id / HW4;
    int pos = id - nc * HW4;

    float4 cv0, cv1, cv2, cv3, cv4, cv5;
    {
        const float4* cf = (const float4*)(coef + (size_t)nc * 24);
        cv0 = cf[0]; cv1 = cf[1]; cv2 = cf[2]; cv3 = cf[3]; cv4 = cf[4]; cv5 = cf[5];
    }
    float cfs[24];
    cfs[0]=cv0.x; cfs[1]=cv0.y; cfs[2]=cv0.z; cfs[3]=cv0.w;
    cfs[4]=cv1.x; cfs[5]=cv1.y; cfs[6]=cv1.z; cfs[7]=cv1.w;
    cfs[8]=cv2.x; cfs[9]=cv2.y; cfs[10]=cv2.z; cfs[11]=cv2.w;
    cfs[12]=cv3.x; cfs[13]=cv3.y; cfs[14]=cv3.z; cfs[15]=cv3.w;
    cfs[16]=cv4.x; cfs[17]=cv4.y; cfs[18]=cv4.z; cfs[19]=cv4.w;
    cfs[20]=cv5.x; cfs[21]=cv5.y; cfs[22]=cv5.z; cfs[23]=cv5.w;

    int n = nc >> 8;
    int c = nc & 255;
    size_t base = ((size_t)(n * TT) * CC + c) * HW;
    const f32x4* xp = (const f32x4*)(x + base);
    f32x4* op = (f32x4*)(out + base);
    const size_t ts = (size_t)CC * HW4;

    f32x4 xv[TT];
    #pragma unroll
    for (int t = 0; t < TT; ++t) xv[t] = __builtin_nontemporal_load(&xp[(size_t)t * ts + pos]);

    const f32x4 zero = {0.f, 0.f, 0.f, 0.f};
    #pragma unroll
    for (int t = 0; t < TT; ++t) {
        float c0 = cfs[t * 3 + 0], c1 = cfs[t * 3 + 1], c2 = cfs[t * 3 + 2];
        f32x4 a = (t > 0)      ? xv[t - 1] : zero;
        f32x4 b =                xv[t];
        f32x4 d = (t < TT - 1) ? xv[t + 1] : zero;
        f32x4 r = c0 * a + c1 * b + c2 * d;
        __builtin_nontemporal_store(r, &op[(size_t)t * ts + pos]);
    }
}

extern "C" void kernel_launch(void* const* d_in, const int* in_sizes, int n_in,
                              void* d_out, int out_size, void* d_ws, size_t ws_size,
                              hipStream_t stream) {
    const float* x          = (const float*)d_in[0];
    const float* g_w1       = (const float*)d_in[1];
    const float* g_bn_gamma = (const float*)d_in[2];
    const float* g_bn_beta  = (const float*)d_in[3];
    const float* g_bn_mean  = (const float*)d_in[4];
    const float* g_bn_var   = (const float*)d_in[5];
    const float* g_w2       = (const float*)d_in[6];
    const float* l_w1       = (const float*)d_in[7];
    const float* l_bn_gamma = (const float*)d_in[8];
    const float* l_bn_beta  = (const float*)d_in[9];
    const float* l_bn_mean  = (const float*)d_in[10];
    const float* l_bn_var   = (const float*)d_in[11];
    const float* l_w2       = (const float*)d_in[12];
    float* out = (float*)d_out;

    float* pooled = (float*)d_ws;                     // 16384 floats
    float* szws   = pooled + NCLIP * CC * TT;         // 4096 floats
    float* coef   = szws + NCLIP * C4 * TT;           // 49152 floats

    tam_pool<<<NCLIP * CC * TT, 256, 0, stream>>>(x, pooled);
    tam_branch_a<<<NCLIP * C4, 256, 0, stream>>>(pooled, l_w1,
        l_bn_gamma, l_bn_beta, l_bn_mean, l_bn_var, szws);
    tam_branch_b<<<NCLIP * 8, 256, 0, stream>>>(pooled, szws, l_w2,
        g_w1, g_bn_gamma, g_bn_beta, g_bn_mean, g_bn_var, g_w2, coef);
    tam_apply<<<(NCLIP * CC * HW4) / 256, 256, 0, stream>>>(x, coef, out);
}

// Round 7
// 99.595 us; speedup vs baseline: 1.0575x; 1.0575x over previous
//
#include <hip/hip_runtime.h>
#include <math.h>

#define TT 8
#define CC 256
#define C4 64
#define KK 3
#define HW 3136    // 56*56
#define HW4 784    // HW/4
#define NCLIP 8
#define BN_EPS 1e-5f

typedef float f32x4 __attribute__((ext_vector_type(4)));

// ---------------- Kernel 1: spatial mean pool ----------------
// pooled[n][c][t] = mean over 56x56 of x[(n*8+t), c, :, :]
// Regular (allocating) loads: this pass populates L3 with x for tam_apply.
__global__ __launch_bounds__(256) void tam_pool(const float* __restrict__ x,
                                                float* __restrict__ pooled) {
    int b = blockIdx.x;            // b = n*2048 + c*8 + t
    int n = b >> 11;
    int c = (b >> 3) & 255;
    int t = b & 7;
    const float4* xr = (const float4*)(x + ((size_t)((n * TT + t) * CC + c)) * HW);
    float s = 0.f;
    for (int i = threadIdx.x; i < HW4; i += 256) {
        float4 v = xr[i];
        s += v.x + v.y + v.z + v.w;
    }
    #pragma unroll
    for (int off = 32; off > 0; off >>= 1) s += __shfl_down(s, off, 64);
    __shared__ float ls[4];
    int lane = threadIdx.x & 63, wv = threadIdx.x >> 6;
    if (lane == 0) ls[wv] = s;
    __syncthreads();
    if (threadIdx.x == 0) {
        float tot = ls[0] + ls[1] + ls[2] + ls[3];
        pooled[(n * CC + c) * TT + t] = tot * (1.f / (float)HW);
    }
}

// ---------------- Kernel 2a: L-branch conv1 + BN + ReLU ----------------
__global__ __launch_bounds__(256) void tam_branch_a(
    const float* __restrict__ pooled, const float* __restrict__ l_w1,
    const float* __restrict__ l_bn_gamma, const float* __restrict__ l_bn_beta,
    const float* __restrict__ l_bn_mean, const float* __restrict__ l_bn_var,
    float* __restrict__ szws)          // [8][64][8]
{
    int n = blockIdx.x >> 6;
    int j = blockIdx.x & 63;
    int tid = threadIdx.x;
    __shared__ float sw[CC * KK];      // l_w1 row j: [i*3+k]
    __shared__ float sp[CC * 9];       // pooled clip n, rows padded to 9
    __shared__ float red[4][8];

    const float4* wsrc = (const float4*)(l_w1 + (size_t)j * (CC * KK));
    if (tid < 192) {
        float4 v = wsrc[tid];
        float* d = sw + tid * 4;
        d[0] = v.x; d[1] = v.y; d[2] = v.z; d[3] = v.w;
    }
    const float4* psrc = (const float4*)(pooled + (size_t)n * CC * TT);
    for (int q = tid; q < 512; q += 256) {
        float4 v = psrc[q];
        int c = q >> 1, e = (q & 1) * 4;
        float* d = sp + c * 9 + e;
        d[0] = v.x; d[1] = v.y; d[2] = v.z; d[3] = v.w;
    }
    __syncthreads();

    int t = tid & 7, ic = tid >> 3;    // ic in 0..31, 8 i-values each
    float acc = 0.f;
    #pragma unroll
    for (int m = 0; m < 8; ++m) {
        int i = ic * 8 + m;
        float p0 = (t > 0) ? sp[i * 9 + t - 1] : 0.f;
        float p1 =           sp[i * 9 + t];
        float p2 = (t < 7) ? sp[i * 9 + t + 1] : 0.f;
        acc += sw[i * 3 + 0] * p0 + sw[i * 3 + 1] * p1 + sw[i * 3 + 2] * p2;
    }
    acc += __shfl_down(acc, 32, 64);
    acc += __shfl_down(acc, 16, 64);
    acc += __shfl_down(acc, 8, 64);
    int lane = tid & 63, wv = tid >> 6;
    if (lane < 8) red[wv][lane] = acc;
    __syncthreads();
    if (tid < 8) {
        float z = red[0][tid] + red[1][tid] + red[2][tid] + red[3][tid];
        float scale = l_bn_gamma[j] * rsqrtf(l_bn_var[j] + BN_EPS);
        z = (z - l_bn_mean[j]) * scale + l_bn_beta[j];
        szws[((size_t)n * C4 + j) * TT + tid] = fmaxf(z, 0.f);
    }
}

// ---------------- Kernel 2b: act (1x1 conv + sigmoid) + G branch -> coef ----------------
__global__ __launch_bounds__(256) void tam_branch_b(
    const float* __restrict__ pooled, const float* __restrict__ szws,
    const float* __restrict__ l_w2,
    const float* __restrict__ g_w1, const float* __restrict__ g_bn_gamma,
    const float* __restrict__ g_bn_beta, const float* __restrict__ g_bn_mean,
    const float* __restrict__ g_bn_var, const float* __restrict__ g_w2,
    float* __restrict__ coef)
{
    int n = blockIdx.x >> 3;
    int cg = blockIdx.x & 7;           // channels cg*32 .. cg*32+31
    int tid = threadIdx.x;
    __shared__ float ssz[C4 * TT];     // sz[j][t], j-major
    __shared__ float sw2[32 * 65];     // l_w2 rows, padded to 65
    __shared__ float spr[32 * 9];      // pooled rows, padded to 9
    __shared__ float sg1[16 * 8];      // g_w1 [o][i]
    __shared__ float sbn[32];          // scale[o], shift[o]
    __shared__ float sg2[48];          // g_w2 [k][o]

    {
        const float4* s = (const float4*)(szws + (size_t)n * C4 * TT);
        if (tid < 128) ((float4*)ssz)[tid] = s[tid];
        const float4* p = (const float4*)(pooled + ((size_t)n * CC + cg * 32) * TT);
        if (tid >= 128 && tid < 192) {
            int q = tid - 128;
            float4 v = p[q];
            int cc = q >> 1, e = (q & 1) * 4;
            float* d = spr + cc * 9 + e;
            d[0] = v.x; d[1] = v.y; d[2] = v.z; d[3] = v.w;
        }
        if (tid >= 192 && tid < 224) ((float4*)sg1)[tid - 192] = ((const float4*)g_w1)[tid - 192];
        if (tid >= 224 && tid < 240) {
            int o = tid - 224;
            float sc = g_bn_gamma[o] * rsqrtf(g_bn_var[o] + BN_EPS);
            sbn[o] = sc;
            sbn[16 + o] = g_bn_beta[o] - g_bn_mean[o] * sc;
        }
    }
    {
        const float4* w = (const float4*)(l_w2 + (size_t)(cg * 32) * C4);
        for (int q = tid; q < 512; q += 256) {
            float4 v = w[q];
            int cc = q >> 4, e = (q & 15) * 4;
            float* d = sw2 + cc * 65 + e;
            d[0] = v.x; d[1] = v.y; d[2] = v.z; d[3] = v.w;
        }
        if (tid < 48) sg2[tid] = g_w2[tid];
    }
    __syncthreads();

    int t = tid & 7, cc = tid >> 3;    // cc in 0..31
    float a = 0.f;
    #pragma unroll 16
    for (int j = 0; j < C4; ++j) a += sw2[cc * 65 + j] * ssz[j * TT + t];
    float act = 1.f / (1.f + __expf(-a));

    float y[16];
    #pragma unroll
    for (int o = 0; o < 16; ++o) {
        float s = 0.f;
        #pragma unroll
        for (int i = 0; i < TT; ++i) s += sg1[o * 8 + i] * spr[cc * 9 + i];
        y[o] = fmaxf(s * sbn[o] + sbn[16 + o], 0.f);
    }
    float k3[KK];
    float mx = -1e30f;
    #pragma unroll
    for (int kk = 0; kk < KK; ++kk) {
        float s = 0.f;
        #pragma unroll
        for (int o = 0; o < 16; ++o) s += sg2[kk * 16 + o] * y[o];
        k3[kk] = s;
        mx = fmaxf(mx, s);
    }
    float se = 0.f;
    #pragma unroll
    for (int kk = 0; kk < KK; ++kk) { k3[kk] = __expf(k3[kk] - mx); se += k3[kk]; }
    float inv = 1.f / se;

    int lane = tid & 63;
    float am = __shfl(act, lane - 1, 64);   // valid when t>0
    float ap = __shfl(act, lane + 1, 64);   // valid when t<7

    float* cf = coef + ((size_t)(n * CC + cg * 32 + cc)) * 24 + t * 3;
    cf[0] = (t > 0) ? k3[0] * inv * am : 0.f;
    cf[1] =           k3[1] * inv * act;
    cf[2] = (t < 7) ? k3[2] * inv * ap : 0.f;
}

// ---------------- Kernel 3: gated temporal depthwise conv ----------------
// Regular loads for x (NT loads measured -5.6us, R6). NT stores keep `out`
// from polluting L3 (+22us, R1->R3). Reversed block order (null, kept —
// harmless LIFO chaining with pool).
__global__ __launch_bounds__(256) void tam_apply(const float* __restrict__ x,
                                                 const float* __restrict__ coef,
                                                 float* __restrict__ out)
{
    int bid = gridDim.x - 1 - blockIdx.x;      // reversed block order
    int id = bid * 256 + threadIdx.x;          // 0 .. 2048*784-1 (exact)
    int nc = id / HW4;
    int pos = id - nc * HW4;

    float4 cv0, cv1, cv2, cv3, cv4, cv5;
    {
        const float4* cf = (const float4*)(coef + (size_t)nc * 24);
        cv0 = cf[0]; cv1 = cf[1]; cv2 = cf[2]; cv3 = cf[3]; cv4 = cf[4]; cv5 = cf[5];
    }
    float cfs[24];
    cfs[0]=cv0.x; cfs[1]=cv0.y; cfs[2]=cv0.z; cfs[3]=cv0.w;
    cfs[4]=cv1.x; cfs[5]=cv1.y; cfs[6]=cv1.z; cfs[7]=cv1.w;
    cfs[8]=cv2.x; cfs[9]=cv2.y; cfs[10]=cv2.z; cfs[11]=cv2.w;
    cfs[12]=cv3.x; cfs[13]=cv3.y; cfs[14]=cv3.z; cfs[15]=cv3.w;
    cfs[16]=cv4.x; cfs[17]=cv4.y; cfs[18]=cv4.z; cfs[19]=cv4.w;
    cfs[20]=cv5.x; cfs[21]=cv5.y; cfs[22]=cv5.z; cfs[23]=cv5.w;

    int n = nc >> 8;
    int c = nc & 255;
    size_t base = ((size_t)(n * TT) * CC + c) * HW;
    const float4* xp = (const float4*)(x + base);
    f32x4* op = (f32x4*)(out + base);
    const size_t ts = (size_t)CC * HW4;

    float4 xv[TT];
    #pragma unroll
    for (int t = 0; t < TT; ++t) xv[t] = xp[(size_t)t * ts + pos];

    #pragma unroll
    for (int t = 0; t < TT; ++t) {
        float c0 = cfs[t * 3 + 0], c1 = cfs[t * 3 + 1], c2 = cfs[t * 3 + 2];
        float4 a = (t > 0)      ? xv[t - 1] : make_float4(0.f, 0.f, 0.f, 0.f);
        float4 b =                xv[t];
        float4 d = (t < TT - 1) ? xv[t + 1] : make_float4(0.f, 0.f, 0.f, 0.f);
        f32x4 r;
        r.x = c0 * a.x + c1 * b.x + c2 * d.x;
        r.y = c0 * a.y + c1 * b.y + c2 * d.y;
        r.z = c0 * a.z + c1 * b.z + c2 * d.z;
        r.w = c0 * a.w + c1 * b.w + c2 * d.w;
        __builtin_nontemporal_store(r, &op[(size_t)t * ts + pos]);
    }
}

extern "C" void kernel_launch(void* const* d_in, const int* in_sizes, int n_in,
                              void* d_out, int out_size, void* d_ws, size_t ws_size,
                              hipStream_t stream) {
    const float* x          = (const float*)d_in[0];
    const float* g_w1       = (const float*)d_in[1];
    const float* g_bn_gamma = (const float*)d_in[2];
    const float* g_bn_beta  = (const float*)d_in[3];
    const float* g_bn_mean  = (const float*)d_in[4];
    const float* g_bn_var   = (const float*)d_in[5];
    const float* g_w2       = (const float*)d_in[6];
    const float* l_w1       = (const float*)d_in[7];
    const float* l_bn_gamma = (const float*)d_in[8];
    const float* l_bn_beta  = (const float*)d_in[9];
    const float* l_bn_mean  = (const float*)d_in[10];
    const float* l_bn_var   = (const float*)d_in[11];
    const float* l_w2       = (const float*)d_in[12];
    float* out = (float*)d_out;

    float* pooled = (float*)d_ws;                     // 16384 floats
    float* szws   = pooled + NCLIP * CC * TT;         // 4096 floats
    float* coef   = szws + NCLIP * C4 * TT;           // 49152 floats

    tam_pool<<<NCLIP * CC * TT, 256, 0, stream>>>(x, pooled);
    tam_branch_a<<<NCLIP * C4, 256, 0, stream>>>(pooled, l_w1,
        l_bn_gamma, l_bn_beta, l_bn_mean, l_bn_var, szws);
    tam_branch_b<<<NCLIP * 8, 256, 0, stream>>>(pooled, szws, l_w2,
        g_w1, g_bn_gamma, g_bn_beta, g_bn_mean, g_bn_var, g_w2, coef);
    tam_apply<<<(NCLIP * CC * HW4) / 256, 256, 0, stream>>>(x, coef, out);
}